// Round 1
// baseline (297.525 us; speedup 1.0000x reference)
//
#include <hip/hip_runtime.h>
#include <hip/hip_bf16.h>
#include <cmath>

typedef unsigned short u16;
typedef __attribute__((ext_vector_type(8))) short bf16x8;
typedef __attribute__((ext_vector_type(4))) float f32x4;
typedef __attribute__((ext_vector_type(4))) unsigned short u16x4;

// Problem constants: B=8, C=128, H=128, WIN=4, K=3, WS=64, L=16384
// Workspace layout (bytes):
#define OFF_AGG   0u          // 5 stats * 8b * 4w * 128c f32 = 81920
#define OFF_WW    81920u      // 32 f32
#define OFF_R     82048u      // 4*128*9 f32 = 18432
#define OFF_FSUM  100480u     // 128 f32
#define OFF_GKT   100992u     // 4*128*128 f32 = 262144
#define OFF_A     363136u     // 4*128*1152 f32 = 2359296
#define OFF_P     2722432u    // 2359296
#define OFF_M     5081728u    // [w][t][o][c] f32 = 2359296
#define OFF_KEFF  7441024u    // [b][t][o][c] u16 = 2359296
#define OFF_XPAD  9800320u    // [b][130][130][128] u16 = 34611200  (total ~42.4 MB)

__device__ __forceinline__ u16 f2bf(float f) {
  union { float f; unsigned int u; } v; v.f = f;
  unsigned int r = v.u + 0x7FFFu + ((v.u >> 16) & 1u);
  return (u16)(r >> 16);
}

// K1: fp32 x -> padded bf16 image [b][130][130][128]; window boundary aggregates via atomics.
// agg stats: 0=T 1=rowFirst 2=rowLast 3=colFirst 4=colLast, layout [stat][b][w][c]
__global__ void k1_pad_agg(const float* __restrict__ x, u16* __restrict__ xpad,
                           float* __restrict__ agg) {
  const int c = threadIdx.x;      // 0..127
  const int rp = blockIdx.x;      // padded row 0..129
  const int b = blockIdx.y;
  const size_t xpb = ((size_t)b * 130 + rp) * 130 * 128;
  if (rp == 0 || rp == 129) {
    for (int q = 0; q < 130; ++q) xpad[xpb + (size_t)q * 128 + c] = 0;
    return;
  }
  const int r = rp - 1;
  xpad[xpb + c] = 0;
  xpad[xpb + (size_t)129 * 128 + c] = 0;
  const float* xr = x + ((size_t)b * 16384 + (size_t)r * 128) * 128 + c;
  float t0 = 0.f, t1 = 0.f, cF0 = 0.f, cL0 = 0.f, cF1 = 0.f, cL1 = 0.f;
  #pragma unroll 4
  for (int q = 0; q < 128; ++q) {
    float v = xr[(size_t)q * 128];
    xpad[xpb + (size_t)(q + 1) * 128 + c] = f2bf(v);
    if (q < 64) t0 += v; else t1 += v;
    if (q == 0) cF0 = v;
    if (q == 63) cL0 = v;
    if (q == 64) cF1 = v;
    if (q == 127) cL1 = v;
  }
  const int i = r >> 6, rw = r & 63;
  const int a0 = b * 512 + (i * 2) * 128 + c;
  const int a1 = b * 512 + (i * 2 + 1) * 128 + c;
  atomicAdd(&agg[a0], t0);
  atomicAdd(&agg[a1], t1);
  atomicAdd(&agg[3 * 4096 + a0], cF0);
  atomicAdd(&agg[3 * 4096 + a1], cF1);
  atomicAdd(&agg[4 * 4096 + a0], cL0);
  atomicAdd(&agg[4 * 4096 + a1], cL1);
  if (rw == 0)  { atomicAdd(&agg[4096 + a0], t0); atomicAdd(&agg[4096 + a1], t1); }
  if (rw == 63) { atomicAdd(&agg[2 * 4096 + a0], t0); atomicAdd(&agg[2 * 4096 + a1], t1); }
}

// R[w,c,t] = sum_o dc_w[w,o] * conv1_w[w*128+o, c, t]    (4608 outputs, K=128)
__global__ void kR(const float* __restrict__ dc_w, const float* __restrict__ conv1_w,
                   float* __restrict__ R) {
  int gid = blockIdx.x * 256 + threadIdx.x;   // 0..4607
  int w = gid / 1152, m = gid % 1152;
  float s = 0.f;
  for (int o = 0; o < 128; ++o)
    s += dc_w[w * 128 + o] * conv1_w[(size_t)(w * 128 + o) * 1152 + m];
  R[gid] = s;
}

// gkT[w][j][c] = gk_w[c][w][j]
__global__ void kT(const float* __restrict__ gk_w, float* __restrict__ gkT) {
  int gid = blockIdx.x * 256 + threadIdx.x;   // 0..65535
  int w = gid >> 14, j = (gid >> 7) & 127, c = gid & 127;
  gkT[gid] = gk_w[c * 512 + w * 128 + j];
}

// fsum[o] = sum_oc fusion_w[o, 512+oc]
__global__ void kF(const float* __restrict__ fusion_w, float* __restrict__ fsum) {
  int o = threadIdx.x;
  float s = 0.f;
  for (int oc = 0; oc < 128; ++oc) s += fusion_w[o * 640 + 512 + oc];
  fsum[o] = s;
}

// K2: per-batch SE gate ww[b][w] from aggregates (S trick) + exact-gelu MLP + sigmoid
__global__ void k2_ww(const float* __restrict__ x, const float* __restrict__ agg,
                      const float* __restrict__ R, const float* __restrict__ dc_b,
                      const float* __restrict__ l1_w, const float* __restrict__ l1_b,
                      const float* __restrict__ l2_w, const float* __restrict__ l2_b,
                      float* __restrict__ ww) {
  const int b = blockIdx.x;
  const int tid = threadIdx.x;
  const int w = tid >> 6, lane = tid & 63;
  __shared__ float red[4];
  float partial = 0.f;
  const int i = w >> 1, j = w & 1;
  const int r0 = i * 64, s0 = j * 64;
  const size_t base = (size_t)b * 16384 * 128;
  #pragma unroll
  for (int k = 0; k < 2; ++k) {
    const int c = lane * 2 + k;
    const int ai = b * 512 + w * 128 + c;
    float T  = agg[ai];
    float rF = agg[4096 + ai];
    float rL = agg[2 * 4096 + ai];
    float cF = agg[3 * 4096 + ai];
    float cL = agg[4 * 4096 + ai];
    float c00 = x[base + ((size_t)(r0 + 0)  * 128 + (s0 + 0))  * 128 + c];
    float c0L = x[base + ((size_t)(r0 + 0)  * 128 + (s0 + 63)) * 128 + c];
    float cL0 = x[base + ((size_t)(r0 + 63) * 128 + (s0 + 0))  * 128 + c];
    float cLL = x[base + ((size_t)(r0 + 63) * 128 + (s0 + 63)) * 128 + c];
    float S[9];
    S[0] = T - rL - cL + cLL;
    S[1] = T - rL;
    S[2] = T - rL - cF + cL0;
    S[3] = T - cL;
    S[4] = T;
    S[5] = T - cF;
    S[6] = T - rF - cL + c0L;
    S[7] = T - rF;
    S[8] = T - rF - cF + c00;
    const float* Rp = R + (w * 128 + c) * 9;
    #pragma unroll
    for (int t = 0; t < 9; ++t) partial += S[t] * Rp[t];
  }
  for (int off = 32; off > 0; off >>= 1) partial += __shfl_xor(partial, off, 64);
  if (lane == 0) red[w] = partial;
  __syncthreads();
  if (tid == 0) {
    float ww0[4];
    #pragma unroll
    for (int w2 = 0; w2 < 4; ++w2) ww0[w2] = red[w2] * (1.f / 4096.f) + dc_b[w2];
    float h1[16];
    for (int i2 = 0; i2 < 16; ++i2) {
      float s = l1_b[i2];
      #pragma unroll
      for (int w2 = 0; w2 < 4; ++w2) s += l1_w[i2 * 4 + w2] * ww0[w2];
      h1[i2] = 0.5f * s * (1.f + erff(s * 0.70710678118654752f));
    }
    for (int w2 = 0; w2 < 4; ++w2) {
      float s = l2_b[w2];
      for (int i2 = 0; i2 < 16; ++i2) s += l2_w[w2 * 16 + i2] * h1[i2];
      ww[b * 4 + w2] = 1.f / (1.f + expf(-s));
    }
  }
}

// K3: A[w,o,m] = sum_oc fusion_w[o, w*128+oc]*cw[w,oc,m]; P same with fusion_w[o,512+oc]
//     m = c*9+t in [0,1152). Thread computes a float4 of m for one (w,o).
__global__ void k3_AP(const float* __restrict__ fusion_w, const float* __restrict__ conv1_w,
                      float* __restrict__ A, float* __restrict__ P) {
  int gid = blockIdx.x * 256 + threadIdx.x;   // 0..147455
  int w = gid / 36864;
  int rem = gid % 36864;
  int o = rem / 288;
  int m = (rem % 288) * 4;
  const float* fw1 = fusion_w + o * 640 + w * 128;
  const float* fw4 = fusion_w + o * 640 + 512;
  const float* cw = conv1_w + (size_t)w * 128 * 1152 + m;
  float a0 = 0, a1 = 0, a2 = 0, a3 = 0, p0 = 0, p1 = 0, p2 = 0, p3 = 0;
  for (int oc = 0; oc < 128; ++oc) {
    float f1 = fw1[oc], f4 = fw4[oc];
    float4 cv = *(const float4*)(cw + (size_t)oc * 1152);
    a0 += f1 * cv.x; a1 += f1 * cv.y; a2 += f1 * cv.z; a3 += f1 * cv.w;
    p0 += f4 * cv.x; p1 += f4 * cv.y; p2 += f4 * cv.z; p3 += f4 * cv.w;
  }
  float4* Ao = (float4*)(A + (size_t)(w * 128 + o) * 1152 + m);
  float4* Po = (float4*)(P + (size_t)(w * 128 + o) * 1152 + m);
  *Ao = make_float4(a0, a1, a2, a3);
  *Po = make_float4(p0, p1, p2, p3);
}

// K4: M[w][t][o][c] = A[w,o,c*9+t] + sum_j P[w,o,j*9+t] * gkT[w][j][c]
__global__ void k4_M(const float* __restrict__ A, const float* __restrict__ P,
                     const float* __restrict__ gkT, float* __restrict__ M) {
  int gid = blockIdx.x * 256 + threadIdx.x;   // 0..147455
  int w = gid / 36864;
  int rem = gid % 36864;
  int t = rem / 4096;
  int o = (rem % 4096) / 32;
  int c = (rem % 32) * 4;
  const float* Pp = P + (size_t)(w * 128 + o) * 1152 + t;
  const float* Ap = A + (size_t)(w * 128 + o) * 1152 + t;
  const float* g = gkT + w * 16384 + c;
  float acc0 = Ap[(c + 0) * 9], acc1 = Ap[(c + 1) * 9];
  float acc2 = Ap[(c + 2) * 9], acc3 = Ap[(c + 3) * 9];
  for (int j = 0; j < 128; ++j) {
    float pv = Pp[j * 9];
    float4 gv = *(const float4*)(g + j * 128);
    acc0 += pv * gv.x; acc1 += pv * gv.y; acc2 += pv * gv.z; acc3 += pv * gv.w;
  }
  *(float4*)(M + (size_t)((w * 9 + t) * 128 + o) * 128 + c) = make_float4(acc0, acc1, acc2, acc3);
}

// K5: Keff_bf16[b][t][o][c] = sum_w ww[b,w]*M[w][t][o][c] + fsum[o]*gk_b[c]
__global__ void k5_keff(const float* __restrict__ M, const float* __restrict__ ww,
                        const float* __restrict__ fsum, const float* __restrict__ gk_b,
                        u16* __restrict__ keff) {
  int gid = blockIdx.x * 256 + threadIdx.x;   // 0..294911
  int b = gid / 36864;
  int rem = gid % 36864;                      // t*4096 + o*32 + cq
  int o = (rem % 4096) / 32;
  int c = (rem % 32) * 4;
  float w0 = ww[b * 4 + 0], w1 = ww[b * 4 + 1], w2 = ww[b * 4 + 2], w3 = ww[b * 4 + 3];
  int mi = rem * 4;                           // == t*16384 + o*128 + c
  float4 m0 = *(const float4*)(M + 0 * 147456 + mi);
  float4 m1 = *(const float4*)(M + 1 * 147456 + mi);
  float4 m2 = *(const float4*)(M + 2 * 147456 + mi);
  float4 m3 = *(const float4*)(M + 3 * 147456 + mi);
  float fs = fsum[o];
  float4 gb = *(const float4*)(gk_b + c);
  float r0 = w0 * m0.x + w1 * m1.x + w2 * m2.x + w3 * m3.x + fs * gb.x;
  float r1 = w0 * m0.y + w1 * m1.y + w2 * m2.y + w3 * m3.y + fs * gb.y;
  float r2 = w0 * m0.z + w1 * m1.z + w2 * m2.z + w3 * m3.z + fs * gb.z;
  float r3 = w0 * m0.w + w1 * m1.w + w2 * m2.w + w3 * m3.w + fs * gb.w;
  u16x4 st = { f2bf(r0), f2bf(r1), f2bf(r2), f2bf(r3) };
  *(u16x4*)(keff + (size_t)b * 147456 + mi) = st;
}

// K6: per-batch 3x3 C->C conv as 9 accumulated bf16 MFMA GEMMs.
// Block = one (b, image row p): out tile 128 pixels x 128 o; 4 waves in 2x2 (64m x 64n each).
// Weights (32 KB/tap) double-buffered in LDS; A-fragments straight from padded bf16 image (L2).
__global__ __launch_bounds__(256, 2) void k6_conv(
    const u16* __restrict__ xpad, const u16* __restrict__ keff,
    const float* __restrict__ fusion_b, float* __restrict__ out) {
  __shared__ __align__(16) u16 wlds[2][128 * 128];
  const int tid = threadIdx.x;
  const int blk = blockIdx.x;
  const int b = blk & 7;            // XCD affinity: batch <-> XCD
  const int p = blk >> 3;
  const int wid = tid >> 6;
  const int lane = tid & 63;
  const int wm = (wid & 1) * 64;
  const int wn = (wid >> 1) * 64;
  const int quad = lane >> 4;
  const int l16 = lane & 15;

  f32x4 acc[4][4];
  #pragma unroll
  for (int i = 0; i < 4; ++i)
    #pragma unroll
    for (int j = 0; j < 4; ++j)
      acc[i][j] = (f32x4){0.f, 0.f, 0.f, 0.f};

  const u16* kb = keff + (size_t)b * 147456;
  bf16x8 streg[8];

  auto stage_load = [&](int tap) {
    const u16* src = kb + tap * 16384;
    #pragma unroll
    for (int it = 0; it < 8; ++it)
      streg[it] = *(const bf16x8*)(src + (it * 256 + tid) * 8);
  };
  auto stage_write = [&](int bufi) {
    u16* dst = &wlds[bufi][0];
    #pragma unroll
    for (int it = 0; it < 8; ++it)
      *(bf16x8*)(dst + (it * 256 + tid) * 8) = streg[it];
  };

  stage_load(0);
  stage_write(0);
  __syncthreads();

  const size_t xrow = 130 * 128;
  const u16* xb = xpad + (size_t)b * 130 * xrow;

  for (int tap = 0; tap < 9; ++tap) {
    if (tap < 8) stage_load(tap + 1);           // overlaps with MFMA below
    const int dh = tap / 3 - 1;
    const int dw = tap % 3 - 1;
    const u16* arow = xb + (size_t)(p + 1 + dh) * xrow + (size_t)(1 + dw) * 128;
    const u16* wbuf = &wlds[tap & 1][0];
    #pragma unroll
    for (int kc = 0; kc < 4; ++kc) {
      const int c0 = kc * 32 + quad * 8;
      bf16x8 a[4], bb[4];
      #pragma unroll
      for (int i = 0; i < 4; ++i)
        a[i] = *(const bf16x8*)(arow + (size_t)(wm + i * 16 + l16) * 128 + c0);
      #pragma unroll
      for (int j = 0; j < 4; ++j)
        bb[j] = *(const bf16x8*)(wbuf + (wn + j * 16 + l16) * 128 + c0);
      #pragma unroll
      for (int i = 0; i < 4; ++i)
        #pragma unroll
        for (int j = 0; j < 4; ++j)
          acc[i][j] = __builtin_amdgcn_mfma_f32_16x16x32_bf16(a[i], bb[j], acc[i][j], 0, 0, 0);
    }
    if (tap < 8) stage_write((tap + 1) & 1);
    __syncthreads();
  }

  float fb[4];
  #pragma unroll
  for (int j = 0; j < 4; ++j) fb[j] = fusion_b[wn + j * 16 + l16];
  float* outb = out + ((size_t)b * 16384 + (size_t)p * 128) * 128;
  #pragma unroll
  for (int i = 0; i < 4; ++i)
    #pragma unroll
    for (int r = 0; r < 4; ++r) {
      const int m = wm + i * 16 + quad * 4 + r;
      #pragma unroll
      for (int j = 0; j < 4; ++j)
        outb[(size_t)m * 128 + (wn + j * 16 + l16)] = acc[i][j][r] + fb[j];
    }
}

extern "C" void kernel_launch(void* const* d_in, const int* in_sizes, int n_in,
                              void* d_out, int out_size, void* d_ws, size_t ws_size,
                              hipStream_t stream) {
  const float* x        = (const float*)d_in[0];
  const float* conv1_w  = (const float*)d_in[1];
  const float* dc_w     = (const float*)d_in[2];
  const float* dc_b     = (const float*)d_in[3];
  const float* l1_w     = (const float*)d_in[4];
  const float* l1_b     = (const float*)d_in[5];
  const float* l2_w     = (const float*)d_in[6];
  const float* l2_b     = (const float*)d_in[7];
  const float* gk_w     = (const float*)d_in[8];
  const float* gk_b     = (const float*)d_in[9];
  const float* fusion_w = (const float*)d_in[10];
  const float* fusion_b = (const float*)d_in[11];
  float* out = (float*)d_out;
  char* ws = (char*)d_ws;

  float* agg  = (float*)(ws + OFF_AGG);
  float* ww   = (float*)(ws + OFF_WW);
  float* R    = (float*)(ws + OFF_R);
  float* fsum = (float*)(ws + OFF_FSUM);
  float* gkT  = (float*)(ws + OFF_GKT);
  float* A    = (float*)(ws + OFF_A);
  float* P    = (float*)(ws + OFF_P);
  float* M    = (float*)(ws + OFF_M);
  u16* keff   = (u16*)(ws + OFF_KEFF);
  u16* xpad   = (u16*)(ws + OFF_XPAD);

  hipMemsetAsync(agg, 0, 81920, stream);
  k1_pad_agg<<<dim3(130, 8), 128, 0, stream>>>(x, xpad, agg);
  kR<<<18, 256, 0, stream>>>(dc_w, conv1_w, R);
  kT<<<256, 256, 0, stream>>>(gk_w, gkT);
  kF<<<1, 128, 0, stream>>>(fusion_w, fsum);
  k2_ww<<<8, 256, 0, stream>>>(x, agg, R, dc_b, l1_w, l1_b, l2_w, l2_b, ww);
  k3_AP<<<576, 256, 0, stream>>>(fusion_w, conv1_w, A, P);
  k4_M<<<576, 256, 0, stream>>>(A, P, gkT, M);
  k5_keff<<<1152, 256, 0, stream>>>(M, ww, fsum, gk_b, keff);
  k6_conv<<<1024, 256, 0, stream>>>(xpad, keff, fusion_b, out);
}